// Round 12
// baseline (19463.258 us; speedup 1.0000x reference)
//
#include <hip/hip_runtime.h>
#include <hip/hip_bf16.h>

#define S_LEN 8192
#define CLEN 16
#define WDIM 256
#define CDIM 64
#define CHID 128
#define WHID 512
#define GDIM 2048   // 4*WHID
#define NTAG 64
#define KDIM 384    // WDIM + CHID
#define NWG 32      // workgroups in sequential kernel

typedef unsigned long long u64;

__device__ __forceinline__ float sigmoidf_(float x) {
  return 1.0f / (1.0f + __expf(-x));
}
__device__ __forceinline__ float tanhf_(float x) {
  // safe tanh: 1 - 2/(e^{2x}+1); correct limits at +-inf without NaN
  return 1.0f - 2.0f / (__expf(2.0f * x) + 1.0f);
}

// ---------------------------------------------------------------------------
// K1: batched char LSTM. 16 words per block (two groups of 8), 256 threads.
// ---------------------------------------------------------------------------
__global__ __launch_bounds__(256)
void char_lstm_kernel(const int* __restrict__ chars, const int* __restrict__ lengths,
                      const float* __restrict__ emb, const float* __restrict__ Wih,
                      const float* __restrict__ Whh, const float* __restrict__ bih,
                      const float* __restrict__ bhh, float* __restrict__ cf)
{
  __shared__ float xs[16][CDIM];
  __shared__ float hsm[16][CHID];
  __shared__ int cidx[16];
  __shared__ int lens[16];
  const int tid = threadIdx.x;
  const int grp = tid >> 7;      // 0..1 (word group)
  const int j = tid & 127;       // hidden index
  const int wb = blockIdx.x * 16;

  for (int i = tid; i < 16 * CHID; i += 256) (&hsm[0][0])[i] = 0.f;
  if (tid < 16) lens[tid] = lengths[wb + tid];
  float c[8];
#pragma unroll
  for (int w = 0; w < 8; ++w) c[w] = 0.f;
  const float bi = bih[j] + bhh[j];
  const float bf = bih[CHID + j] + bhh[CHID + j];
  const float bg = bih[2 * CHID + j] + bhh[2 * CHID + j];
  const float bo = bih[3 * CHID + j] + bhh[3 * CHID + j];

  for (int t = 0; t < CLEN; ++t) {
    __syncthreads();
    if (tid < 16) cidx[tid] = chars[(wb + tid) * CLEN + t];
    __syncthreads();
    {
      int e = tid * 4;
      int wi = e >> 6;
      int k = e & 63;
      const float4 v = *(const float4*)(emb + (size_t)cidx[wi] * CDIM + k);
      *(float4*)(&xs[wi][k]) = v;
    }
    __syncthreads();
    float ai[8], af[8], ag[8], ao[8];
#pragma unroll
    for (int w = 0; w < 8; ++w) { ai[w] = bi; af[w] = bf; ag[w] = bg; ao[w] = bo; }
    // x part (K = 64)
    for (int k = 0; k < CDIM; k += 4) {
      float4 w0 = *(const float4*)(Wih + (size_t)j * CDIM + k);
      float4 w1 = *(const float4*)(Wih + (size_t)(CHID + j) * CDIM + k);
      float4 w2 = *(const float4*)(Wih + (size_t)(2 * CHID + j) * CDIM + k);
      float4 w3 = *(const float4*)(Wih + (size_t)(3 * CHID + j) * CDIM + k);
#pragma unroll
      for (int s = 0; s < 4; ++s) {
        float wiv = (&w0.x)[s], wfv = (&w1.x)[s], wgv = (&w2.x)[s], wov = (&w3.x)[s];
#pragma unroll
        for (int w = 0; w < 8; ++w) {
          float xv = xs[grp * 8 + w][k + s];   // wave-uniform -> LDS broadcast
          ai[w] = fmaf(wiv, xv, ai[w]);
          af[w] = fmaf(wfv, xv, af[w]);
          ag[w] = fmaf(wgv, xv, ag[w]);
          ao[w] = fmaf(wov, xv, ao[w]);
        }
      }
    }
    // h part (K = 128)
    for (int k = 0; k < CHID; k += 4) {
      float4 w0 = *(const float4*)(Whh + (size_t)j * CHID + k);
      float4 w1 = *(const float4*)(Whh + (size_t)(CHID + j) * CHID + k);
      float4 w2 = *(const float4*)(Whh + (size_t)(2 * CHID + j) * CHID + k);
      float4 w3 = *(const float4*)(Whh + (size_t)(3 * CHID + j) * CHID + k);
#pragma unroll
      for (int s = 0; s < 4; ++s) {
        float wiv = (&w0.x)[s], wfv = (&w1.x)[s], wgv = (&w2.x)[s], wov = (&w3.x)[s];
#pragma unroll
        for (int w = 0; w < 8; ++w) {
          float hv = hsm[grp * 8 + w][k + s];
          ai[w] = fmaf(wiv, hv, ai[w]);
          af[w] = fmaf(wfv, hv, af[w]);
          ag[w] = fmaf(wgv, hv, ag[w]);
          ao[w] = fmaf(wov, hv, ao[w]);
        }
      }
    }
    __syncthreads();
#pragma unroll
    for (int w = 0; w < 8; ++w) {
      if (t < lens[grp * 8 + w]) {
        float iv = sigmoidf_(ai[w]);
        float fv = sigmoidf_(af[w]);
        float gv = tanhf_(ag[w]);
        float ov = sigmoidf_(ao[w]);
        c[w] = fv * c[w] + iv * gv;
        hsm[grp * 8 + w][j] = ov * tanhf_(c[w]);
      }
    }
  }
#pragma unroll
  for (int w = 0; w < 8; ++w)
    cf[(size_t)(wb + grp * 8 + w) * CHID + j] = c[w];   // feature = final CELL state
}

// ---------------------------------------------------------------------------
// K3: sequential word LSTM, v12 = R3 (proven 13.88 ms) + x-GEMM folded into
// the poll-wait shadow. The gx_gemm kernel and 64 MB Gx buffer are GONE.
//
// 32 WGs x 256 thr. Wave cc owns h-chunk [128cc,+128) and x-chunk
// [96cc,+96) of the concatenated input [we(x_t) | cf_t] (384). Per step:
//  A. stage x-chunk (wave-private: lanes 0..23 load float4 from word_emb /
//     char_feat; 256%4==0 so a float4 never straddles the we|cf boundary);
//     issued BEFORE the poll -> gather latency hides under the wait.
//  B. R3 tagged-slot poll (atomic u64, no tearing), h-chunk stage.
//  C. matvec = 32 float4 FMA (Whh, L2-streamed wl pattern -- R9 proved this
//     beats LDS-resident at 1 WG/CU) + 24 float4 FMA (Wih, same pattern).
//  D. red write -> ONE barrier -> wave0 finalize with register bias
//     (bih+bhh, replaces the Gx-baked bias), publish, hs store.
// No new inter-block sync of any kind (R5/R11 lesson: multi-role gated
// kernels hang unpredictably on this part; never again).
// ---------------------------------------------------------------------------
__global__ __launch_bounds__(256, 1)
void word_lstm_seq(const float* __restrict__ Whh, const float* __restrict__ Wih,
                   const float* __restrict__ bih, const float* __restrict__ bhh,
                   const int* __restrict__ x, const float* __restrict__ word_emb,
                   const float* __restrict__ cf,
                   float* __restrict__ hs, u64* hbuf)
{
  __shared__ float h_lds[WHID];
  __shared__ float x_lds[KDIM];
  __shared__ float red[2][256];
  const int tid  = threadIdx.x;
  const int wg   = blockIdx.x;
  const int cc   = tid >> 6;     // chunk 0..3 (one per wave)
  const int lane = tid & 63;
  const int kb   = cc * 128;     // h-chunk base
  const int xb   = cc * 96;      // x-chunk base
  const int grow = (lane >> 4) * WHID + wg * 16 + (lane & 15);

  // weight fragments -- compiler streams these from L2 inside the loop
  // (VGPR ~84 codegen, measured faster than LDS-resident at 1 WG/CU in R9)
  float wl[128];
  {
    const float* wsrc = Whh + (size_t)grow * WHID + kb;
#pragma unroll
    for (int k = 0; k < 128; ++k) wl[k] = wsrc[k];
  }
  float wx[96];
  {
    const float* wsrc = Wih + (size_t)grow * KDIM + xb;
#pragma unroll
    for (int k = 0; k < 96; ++k) wx[k] = wsrc[k];
  }
  const float bias = bih[grow] + bhh[grow];   // replaces Gx-baked bias

  float c_state = 0.f;   // lanes<16 of wave 0 use

  for (int t = 0; t < S_LEN; ++t) {
    const int par = t & 1;
    // ---- A. stage x-chunk (wave-private; issued before the poll) ----
    {
      const int xt = x[t];
      if (lane < 24) {
        const int gk = xb + 4 * lane;
        float4 v = (gk < WDIM)
            ? *(const float4*)(word_emb + (size_t)xt * WDIM + gk)
            : *(const float4*)(cf + (size_t)t * CHID + (gk - WDIM));
        *(float4*)(&x_lds[gk]) = v;
      }
    }
    // ---- B. poll own 2 tagged slots (atomic u64: tag+value together) ----
    float v0 = 0.f, v1 = 0.f;
    if (t > 0) {
      const u64* ps = hbuf + (size_t)par * WHID + kb + 2 * lane;
      const unsigned want = (unsigned)t;
      u64 a, b;
      do {
        a = __hip_atomic_load(ps + 0, __ATOMIC_RELAXED, __HIP_MEMORY_SCOPE_AGENT);
        b = __hip_atomic_load(ps + 1, __ATOMIC_RELAXED, __HIP_MEMORY_SCOPE_AGENT);
      } while (((unsigned)(a >> 32) != want) | ((unsigned)(b >> 32) != want));
      v0 = __uint_as_float((unsigned)a);
      v1 = __uint_as_float((unsigned)b);
    }
    *(float2*)(&h_lds[kb + 2 * lane]) = make_float2(v0, v1);
    __threadfence_block();   // wave-synchronous: covers x_lds + h_lds writes
    // ---- C. matvec: h part (Whh) + x part (Wih), h/x broadcast from LDS ----
    float acc = 0.f;
#pragma unroll
    for (int g = 0; g < 32; ++g) {
      float4 hv = *(const float4*)(&h_lds[kb + 4 * g]);
      acc = fmaf(wl[4 * g + 0], hv.x, acc);
      acc = fmaf(wl[4 * g + 1], hv.y, acc);
      acc = fmaf(wl[4 * g + 2], hv.z, acc);
      acc = fmaf(wl[4 * g + 3], hv.w, acc);
    }
#pragma unroll
    for (int g = 0; g < 24; ++g) {
      float4 xv = *(const float4*)(&x_lds[xb + 4 * g]);
      acc = fmaf(wx[4 * g + 0], xv.x, acc);
      acc = fmaf(wx[4 * g + 1], xv.y, acc);
      acc = fmaf(wx[4 * g + 2], xv.z, acc);
      acc = fmaf(wx[4 * g + 3], xv.w, acc);
    }
    red[par][tid] = acc;
    __syncthreads();   // the ONLY barrier per step
    // ---- D. wave0 finalize + publish (R3 verbatim, bias from register) ----
    if (tid < 64) {
      const float* rp = red[par];
      float s = rp[tid] + rp[64 + tid] + rp[128 + tid] + rp[192 + tid] + bias;
      float act = ((tid >> 4) == 2) ? tanhf_(s) : sigmoidf_(s);
      int jj = tid & 15;
      float iv = __shfl(act, jj);
      float fv = __shfl(act, 16 + jj);
      float gv = __shfl(act, 32 + jj);
      float ov = __shfl(act, 48 + jj);
      if (tid < 16) {
        c_state = fv * c_state + iv * gv;
        float hv = ov * tanhf_(c_state);
        const int hidx = wg * 16 + tid;
        const u64 pkt = ((u64)(unsigned)(t + 1) << 32) | (u64)__float_as_uint(hv);
        (void)__hip_atomic_exchange(&hbuf[(size_t)((t + 1) & 1) * WHID + hidx],
                                    pkt, __ATOMIC_RELAXED,
                                    __HIP_MEMORY_SCOPE_AGENT);
        hs[(size_t)t * WHID + hidx] = hv;
      }
    }
  }
}

// ---------------------------------------------------------------------------
// K4: logits + log_softmax. One 64-lane wave per row t; lane = tag.
// ---------------------------------------------------------------------------
__global__ __launch_bounds__(256)
void tag_kernel(const float* __restrict__ hs, const float* __restrict__ W,
                const float* __restrict__ b, float* __restrict__ out)
{
  const int wave = threadIdx.x >> 6;
  const int lane = threadIdx.x & 63;
  const int t = blockIdx.x * 4 + wave;
  const float* hr = hs + (size_t)t * WHID;
  const float* wr = W + (size_t)lane * WHID;
  float acc = b[lane];
  for (int k = 0; k < WHID; k += 4) {
    float4 wv = *(const float4*)(wr + k);
    float4 hv = *(const float4*)(hr + k);
    acc = fmaf(wv.x, hv.x, acc);
    acc = fmaf(wv.y, hv.y, acc);
    acc = fmaf(wv.z, hv.z, acc);
    acc = fmaf(wv.w, hv.w, acc);
  }
  float m = acc;
#pragma unroll
  for (int off = 32; off > 0; off >>= 1) m = fmaxf(m, __shfl_xor(m, off));
  float e = __expf(acc - m);
  float sum = e;
#pragma unroll
  for (int off = 32; off > 0; off >>= 1) sum += __shfl_xor(sum, off);
  out[(size_t)t * NTAG + lane] = (acc - m) - __logf(sum);
}

extern "C" void kernel_launch(void* const* d_in, const int* in_sizes, int n_in,
                              void* d_out, int out_size, void* d_ws, size_t ws_size,
                              hipStream_t stream)
{
  const int* x          = (const int*)d_in[0];
  const int* chars      = (const int*)d_in[1];
  const int* lengths    = (const int*)d_in[2];
  const float* word_emb = (const float*)d_in[3];
  const float* char_emb = (const float*)d_in[4];
  const float* c_Wih    = (const float*)d_in[5];
  const float* c_Whh    = (const float*)d_in[6];
  const float* c_bih    = (const float*)d_in[7];
  const float* c_bhh    = (const float*)d_in[8];
  const float* w_Wih    = (const float*)d_in[9];
  const float* w_Whh    = (const float*)d_in[10];
  const float* w_bih    = (const float*)d_in[11];
  const float* w_bhh    = (const float*)d_in[12];
  const float* lin_W    = (const float*)d_in[13];
  const float* lin_b    = (const float*)d_in[14];
  float* out = (float*)d_out;

  char* ws = (char*)d_ws;
  // layout: [0,8192) hbuf (2 x 512 u64 tagged slots) |
  //         char_feat 4 MiB | hs 16 MiB   (no Gx buffer anymore; ~20 MiB)
  u64*   hbuf      = (u64*)ws;
  float* char_feat = (float*)(ws + 8192);
  float* hs        = (float*)(ws + 8192 + (size_t)S_LEN * CHID * 4);

  // zero tags every call (tag 0 never matches an expected epoch t >= 1)
  hipMemsetAsync(ws, 0, 8192, stream);

  char_lstm_kernel<<<S_LEN / 16, 256, 0, stream>>>(
      chars, lengths, char_emb, c_Wih, c_Whh, c_bih, c_bhh, char_feat);

  word_lstm_seq<<<NWG, 256, 0, stream>>>(w_Whh, w_Wih, w_bih, w_bhh,
                                         x, word_emb, char_feat, hs, hbuf);

  tag_kernel<<<S_LEN / 4, 256, 0, stream>>>(hs, lin_W, lin_b, out);
}